// Round 12
// baseline (95.055 us; speedup 1.0000x reference)
//
#include <hip/hip_runtime.h>

#define TSD 512      // TS (feature dim)
#define SRC 256
#define TGT 256
#define NB  4        // batch
#define KSCALE 2.885390081777927f   // 2*log2(e): exp2(K*x) == exp(2x)
#define ECLAMP 8192.0f              // 2^13: 4-way w-product <= 2^104, overflow-safe

// ---------------------------------------------------------------------------
// Projection GEMM (R9-proven ALU version): 64x64 tiles, 4x4 micro-tile, BK=16.
// z=0: hpE[r][o]    = min(exp2(K*(hid.Wh)[r][o]), ECLAMP)        (row-major)
// z=1: epE[b][o][s] = min(exp2(K*((enc.We)[r][o]+bias[o])), ECLAMP) (TRANSPOSED)
// ---------------------------------------------------------------------------
__global__ __launch_bounds__(256) void proj_kernel(
    const float* __restrict__ hid, const float* __restrict__ enc,
    const float* __restrict__ W, const float* __restrict__ bias,
    float* __restrict__ hpE, float* __restrict__ epE)
{
    const int z = blockIdx.z;
    const float* __restrict__ X = z ? enc : hid;
    const int wofs = z ? TSD : 0;

    __shared__ float Xs[16][68];   // [k][m]
    __shared__ float Ws[16][68];   // [k][n]
    __shared__ float tile[64][68]; // transpose staging (z=1)

    const int tx = threadIdx.x, ty = threadIdx.y;
    const int tid = ty * 16 + tx;
    const int o0 = blockIdx.x * 64;
    const int r0 = blockIdx.y * 64;

    const int m  = tid >> 2;        // 0..63
    const int kq = (tid & 3) * 4;   // 0,4,8,12

    float acc[4][4] = {};

    for (int k0 = 0; k0 < TSD; k0 += 16) {
        __syncthreads();
        float4 av = *reinterpret_cast<const float4*>(&X[(r0 + m) * TSD + k0 + kq]);
        float4 wv = *reinterpret_cast<const float4*>(&W[(o0 + m) * (2 * TSD) + wofs + k0 + kq]);
        Xs[kq + 0][m] = av.x; Xs[kq + 1][m] = av.y; Xs[kq + 2][m] = av.z; Xs[kq + 3][m] = av.w;
        Ws[kq + 0][m] = wv.x; Ws[kq + 1][m] = wv.y; Ws[kq + 2][m] = wv.z; Ws[kq + 3][m] = wv.w;
        __syncthreads();
        #pragma unroll
        for (int k = 0; k < 16; ++k) {
            float4 a  = *reinterpret_cast<const float4*>(&Xs[k][ty * 4]);
            float4 bb = *reinterpret_cast<const float4*>(&Ws[k][tx * 4]);
            float ar[4] = {a.x, a.y, a.z, a.w};
            float br[4] = {bb.x, bb.y, bb.z, bb.w};
            #pragma unroll
            for (int i = 0; i < 4; ++i)
                #pragma unroll
                for (int j = 0; j < 4; ++j)
                    acc[i][j] = fmaf(ar[i], br[j], acc[i][j]);
        }
    }

    if (z) {
        const float b0 = bias[o0 + tx * 4 + 0];
        const float b1 = bias[o0 + tx * 4 + 1];
        const float b2 = bias[o0 + tx * 4 + 2];
        const float b3 = bias[o0 + tx * 4 + 3];
        __syncthreads();
        #pragma unroll
        for (int i = 0; i < 4; ++i) {
            float4 val;
            val.x = fminf(__builtin_amdgcn_exp2f((acc[i][0] + b0) * KSCALE), ECLAMP);
            val.y = fminf(__builtin_amdgcn_exp2f((acc[i][1] + b1) * KSCALE), ECLAMP);
            val.z = fminf(__builtin_amdgcn_exp2f((acc[i][2] + b2) * KSCALE), ECLAMP);
            val.w = fminf(__builtin_amdgcn_exp2f((acc[i][3] + b3) * KSCALE), ECLAMP);
            *reinterpret_cast<float4*>(&tile[ty * 4 + i][tx * 4]) = val;
        }
        __syncthreads();
        const int bb_ = r0 >> 8;
        const int s0  = (r0 & 255) + (tid & 15) * 4;
        #pragma unroll
        for (int it = 0; it < 4; ++it) {
            const int ol = it * 16 + (tid >> 4);
            float4 val;
            val.x = tile[(tid & 15) * 4 + 0][ol];
            val.y = tile[(tid & 15) * 4 + 1][ol];
            val.z = tile[(tid & 15) * 4 + 2][ol];
            val.w = tile[(tid & 15) * 4 + 3][ol];
            *reinterpret_cast<float4*>(&epE[((size_t)bb_ * TSD + o0 + ol) * SRC + s0]) = val;
        }
    } else {
        #pragma unroll
        for (int i = 0; i < 4; ++i) {
            const int r = r0 + ty * 4 + i;
            float4 o4;
            o4.x = fminf(__builtin_amdgcn_exp2f(acc[i][0] * KSCALE), ECLAMP);
            o4.y = fminf(__builtin_amdgcn_exp2f(acc[i][1] * KSCALE), ECLAMP);
            o4.z = fminf(__builtin_amdgcn_exp2f(acc[i][2] * KSCALE), ECLAMP);
            o4.w = fminf(__builtin_amdgcn_exp2f(acc[i][3] * KSCALE), ECLAMP);
            *reinterpret_cast<float4*>(&hpE[r * TSD + o0 + tx * 4]) = o4;
        }
    }
}

__device__ __forceinline__ float wave_red_sum(float v) {
    #pragma unroll
    for (int off = 1; off < 64; off <<= 1) v += __shfl_xor(v, off, 64);
    return v;
}
__device__ __forceinline__ float wave_red_max(float v) {
    #pragma unroll
    for (int off = 1; off < 64; off <<= 1) v = fmaxf(v, __shfl_xor(v, off, 64));
    return v;
}

// one s-column, 4 t-rows: w_t = Eh_t*ee + 1 (inline 1.0); 4 rcps share one.
#define TERM(EE, EH0, EH1, EH2, EH3, VV, A0, A1, A2, A3) {      \
    const float w0_ = fmaf(EH0, (EE), 1.0f);                    \
    const float w1_ = fmaf(EH1, (EE), 1.0f);                    \
    const float w2_ = fmaf(EH2, (EE), 1.0f);                    \
    const float w3_ = fmaf(EH3, (EE), 1.0f);                    \
    const float p01_ = w0_ * w1_;                               \
    const float p23_ = w2_ * w3_;                               \
    const float rv_  = __builtin_amdgcn_rcpf(p01_ * p23_) * (VV); \
    const float rp01_ = rv_ * p01_;                             \
    const float rp23_ = rv_ * p23_;                             \
    A0 = fmaf(rp23_, w1_, A0); A1 = fmaf(rp23_, w0_, A1);       \
    A2 = fmaf(rp01_, w3_, A2); A3 = fmaf(rp01_, w2_, A3); }

// one o-step: 4 s-columns (EE float4), eh components for 4 t, v scalar
#define OSTEP(EE, H0c, H1c, H2c, H3c, VVc)                       \
    TERM((EE).x, H0c, H1c, H2c, H3c, VVc, a00, a10, a20, a30)    \
    TERM((EE).y, H0c, H1c, H2c, H3c, VVc, a01, a11, a21, a31)    \
    TERM((EE).z, H0c, H1c, H2c, H3c, VVc, a02, a12, a22, a32)    \
    TERM((EE).w, H0c, H1c, H2c, H3c, VVc, a03, a13, a23, a33)

// ---------------------------------------------------------------------------
// Phase A: P_z[t][s] = sum_{o in half z} v[o]/(Eh*Ee+1).
// Grid (TGT/4, NB, 2 o-halves), 512 thr = 8 waves; wave owns 32 o;
// lane owns 4 consecutive s (float4 ee). NO LDS in loop; Eh/v wave-uniform
// (scalar pipe); 1-chunk-ahead double-buffered prefetch.
// ---------------------------------------------------------------------------
__global__ __launch_bounds__(512) void score_kernel(
    const float* __restrict__ hpE, const float* __restrict__ epE,
    const float* __restrict__ v, float* __restrict__ Ppart)
{
    __shared__ float accs[4][8][SRC];   // 32 KB

    const int tid = threadIdx.x;
    const int b  = blockIdx.y;
    const int t0 = blockIdx.x * 4;
    const int oh = blockIdx.z;

    const int w    = __builtin_amdgcn_readfirstlane(tid >> 6);  // wave 0..7
    const int lane = tid & 63;
    const int obase = oh * 256 + w * 32;                        // uniform

    const float* __restrict__ epb = epE + (size_t)b * TSD * SRC
                                  + (size_t)obase * SRC + 4 * lane;
    const float* __restrict__ h0 = hpE + (size_t)(b * TGT + t0 + 0) * TSD + obase;
    const float* __restrict__ h1 = hpE + (size_t)(b * TGT + t0 + 1) * TSD + obase;
    const float* __restrict__ h2 = hpE + (size_t)(b * TGT + t0 + 2) * TSD + obase;
    const float* __restrict__ h3 = hpE + (size_t)(b * TGT + t0 + 3) * TSD + obase;
    const float* __restrict__ vb = v + obase;

    float a00=0,a01=0,a02=0,a03=0, a10=0,a11=0,a12=0,a13=0;
    float a20=0,a21=0,a22=0,a23=0, a30=0,a31=0,a32=0,a33=0;

    // prologue: chunk 0 (4 o-steps)
    float4 e0 = *reinterpret_cast<const float4*>(epb + 0 * SRC);
    float4 e1 = *reinterpret_cast<const float4*>(epb + 1 * SRC);
    float4 e2 = *reinterpret_cast<const float4*>(epb + 2 * SRC);
    float4 e3 = *reinterpret_cast<const float4*>(epb + 3 * SRC);
    float4 H0 = *reinterpret_cast<const float4*>(h0);
    float4 H1 = *reinterpret_cast<const float4*>(h1);
    float4 H2 = *reinterpret_cast<const float4*>(h2);
    float4 H3 = *reinterpret_cast<const float4*>(h3);
    float4 V4 = *reinterpret_cast<const float4*>(vb);

    #pragma unroll
    for (int c = 0; c < 8; ++c) {
        float4 f0, f1, f2, f3, G0, G1, G2, G3, W4;
        if (c < 7) {   // issue next chunk's loads BEFORE computing this one
            const int q = 4 * (c + 1);
            f0 = *reinterpret_cast<const float4*>(epb + (size_t)(q + 0) * SRC);
            f1 = *reinterpret_cast<const float4*>(epb + (size_t)(q + 1) * SRC);
            f2 = *reinterpret_cast<const float4*>(epb + (size_t)(q + 2) * SRC);
            f3 = *reinterpret_cast<const float4*>(epb + (size_t)(q + 3) * SRC);
            G0 = *reinterpret_cast<const float4*>(h0 + q);
            G1 = *reinterpret_cast<const float4*>(h1 + q);
            G2 = *reinterpret_cast<const float4*>(h2 + q);
            G3 = *reinterpret_cast<const float4*>(h3 + q);
            W4 = *reinterpret_cast<const float4*>(vb + q);
        }
        OSTEP(e0, H0.x, H1.x, H2.x, H3.x, V4.x)
        OSTEP(e1, H0.y, H1.y, H2.y, H3.y, V4.y)
        OSTEP(e2, H0.z, H1.z, H2.z, H3.z, V4.z)
        OSTEP(e3, H0.w, H1.w, H2.w, H3.w, V4.w)
        if (c < 7) {
            e0 = f0; e1 = f1; e2 = f2; e3 = f3;
            H0 = G0; H1 = G1; H2 = G2; H3 = G3; V4 = W4;
        }
    }

    {   // park partials: accs[t][w][s], s = 4*lane + j
        float4 r0; r0.x = a00; r0.y = a01; r0.z = a02; r0.w = a03;
        float4 r1; r1.x = a10; r1.y = a11; r1.z = a12; r1.w = a13;
        float4 r2; r2.x = a20; r2.y = a21; r2.z = a22; r2.w = a23;
        float4 r3; r3.x = a30; r3.y = a31; r3.z = a32; r3.w = a33;
        *reinterpret_cast<float4*>(&accs[0][w][4 * lane]) = r0;
        *reinterpret_cast<float4*>(&accs[1][w][4 * lane]) = r1;
        *reinterpret_cast<float4*>(&accs[2][w][4 * lane]) = r2;
        *reinterpret_cast<float4*>(&accs[3][w][4 * lane]) = r3;
    }
    __syncthreads();

    // combine 8 waves; thread handles 2 (t,s) pairs
    float* __restrict__ Pz = Ppart + (size_t)oh * (NB * TGT * SRC);
    #pragma unroll
    for (int r = 0; r < 2; ++r) {
        const int idx = tid + r * 512;
        const int t = idx >> 8;
        const int s = idx & 255;
        float Psum = 0.f;
        #pragma unroll
        for (int k = 0; k < 8; ++k) Psum += accs[t][k][s];
        Pz[((size_t)(b * TGT + t0 + t)) * SRC + s] = Psum;
    }
}

// ---------------------------------------------------------------------------
// Phase B: softmax. One wave per target row (4 rows/block). Reads P0+P1 from
// ws, writes final probs to d_out.
// ---------------------------------------------------------------------------
__global__ __launch_bounds__(256) void softmax_kernel(
    const float* __restrict__ Ppart, const int* __restrict__ mask,
    const float* __restrict__ v, float* __restrict__ probs)
{
    const int tid  = threadIdx.x;
    const int lane = tid & 63;
    const int rowg = blockIdx.x * 4 + (tid >> 6);   // b*TGT + t
    const int b    = rowg >> 8;

    float sv = 0.f;
    #pragma unroll
    for (int k = 0; k < 8; ++k) sv += v[lane + 64 * k];
    const float sumv = wave_red_sum(sv);

    const size_t base = (size_t)rowg * SRC + 4 * lane;
    const float4 Pa = *reinterpret_cast<const float4*>(&Ppart[base]);
    const float4 Pb = *reinterpret_cast<const float4*>(&Ppart[base + (size_t)NB * TGT * SRC]);
    float sc[4];
    sc[0] = sumv - 2.f * (Pa.x + Pb.x);
    sc[1] = sumv - 2.f * (Pa.y + Pb.y);
    sc[2] = sumv - 2.f * (Pa.z + Pb.z);
    sc[3] = sumv - 2.f * (Pa.w + Pb.w);

    const float lmax = fmaxf(fmaxf(sc[0], sc[1]), fmaxf(sc[2], sc[3]));
    const float m = wave_red_max(lmax);
    float e[4];
    #pragma unroll
    for (int i = 0; i < 4; ++i) e[i] = __expf(sc[i] - m);
    const float sE = wave_red_sum(e[0] + e[1] + e[2] + e[3]);

    const int4 mk = *reinterpret_cast<const int4*>(&mask[b * SRC + 4 * lane]);
    float mq[4];
    mq[0] = (e[0] / sE) * (float)mk.x;
    mq[1] = (e[1] / sE) * (float)mk.y;
    mq[2] = (e[2] / sE) * (float)mk.z;
    mq[3] = (e[3] / sE) * (float)mk.w;
    const float sM = wave_red_sum(mq[0] + mq[1] + mq[2] + mq[3]);
    const float inv = 1.f / (sM + 1e-12f);
    float4 pv;
    pv.x = mq[0] * inv; pv.y = mq[1] * inv; pv.z = mq[2] * inv; pv.w = mq[3] * inv;
    *reinterpret_cast<float4*>(&probs[base]) = pv;
}

// ---------------------------------------------------------------------------
// Phase C: context. Grid (TGT/4, NB, 2 d-halves), 256 thr.
// ---------------------------------------------------------------------------
__global__ __launch_bounds__(256) void ctx_kernel(
    const float* __restrict__ probs, const float* __restrict__ enc,
    float* __restrict__ ctx_out)
{
    __shared__ float p_lds[4][SRC];

    const int tid = threadIdx.x;
    const int b   = blockIdx.y;
    const int t0  = blockIdx.x * 4;
    const int dh  = blockIdx.z;

    #pragma unroll
    for (int t = 0; t < 4; ++t)
        p_lds[t][tid] = probs[((size_t)(b * TGT + t0 + t)) * SRC + tid];
    __syncthreads();

    const float* __restrict__ encb = enc + (size_t)b * SRC * TSD + dh * 256 + tid;
    float c0 = 0.f, c1 = 0.f, c2 = 0.f, c3 = 0.f;
    #pragma unroll 4
    for (int s2 = 0; s2 < SRC; ++s2) {
        const float ev = encb[(size_t)s2 * TSD];
        c0 = fmaf(p_lds[0][s2], ev, c0);
        c1 = fmaf(p_lds[1][s2], ev, c1);
        c2 = fmaf(p_lds[2][s2], ev, c2);
        c3 = fmaf(p_lds[3][s2], ev, c3);
    }
    const size_t obase = ((size_t)(b * TGT + t0)) * TSD + dh * 256 + tid;
    ctx_out[obase]           = c0;
    ctx_out[obase + TSD]     = c1;
    ctx_out[obase + 2 * TSD] = c2;
    ctx_out[obase + 3 * TSD] = c3;
}

extern "C" void kernel_launch(void* const* d_in, const int* in_sizes, int n_in,
                              void* d_out, int out_size, void* d_ws, size_t ws_size,
                              hipStream_t stream) {
    const float* hid  = (const float*)d_in[0];   // (4,256,512)
    const float* enc  = (const float*)d_in[1];   // (4,256,512)
    const int*   mask = (const int*)  d_in[2];   // (4,256)
    const float* W    = (const float*)d_in[3];   // (512,1024)
    const float* bias = (const float*)d_in[4];   // (512,)
    const float* v    = (const float*)d_in[5];   // (512,)

    float* out   = (float*)d_out;
    float* ctx   = out;                       // 4*256*512
    float* probs = out + NB * TGT * TSD;      // 4*256*256

    float* hpE   = (float*)d_ws;              // 1024*512: clamp(exp2(K*h))   2 MB
    float* epE   = hpE + NB * TGT * TSD;      // 4*512*256: clamp(exp2)^T     2 MB
    float* Ppart = epE + NB * TSD * SRC;      // 2 x 4*256*256 partials       2 MB

    dim3 pb(16, 16);
    dim3 pg(TSD / 64, (NB * TGT) / 64, 2);
    proj_kernel<<<pg, pb, 0, stream>>>(hid, enc, W, bias, hpE, epE);

    dim3 ag(TGT / 4, NB, 2);
    score_kernel<<<ag, 512, 0, stream>>>(hpE, epE, v, Ppart);

    softmax_kernel<<<dim3(NB * TGT / 4), 256, 0, stream>>>(Ppart, mask, v, probs);

    dim3 cg(TGT / 4, NB, 2);
    ctx_kernel<<<cg, 256, 0, stream>>>(probs, enc, ctx);
}

// Round 13
// 71.087 us; speedup vs baseline: 1.3372x; 1.3372x over previous
//
#include <hip/hip_runtime.h>

#define TSD 512      // TS (feature dim)
#define SRC 256
#define TGT 256
#define NB  4        // batch
#define KSCALE 2.885390081777927f       // 2*log2(e): exp2(K*x) == exp(2x)
#define SCALE  9.5367431640625e-07f     // 2^-20: overflow headroom for 4-way product
#define EPSV   1e-20f

// ---------------------------------------------------------------------------
// Projection GEMM (R9-proven): 64x64 tiles, 4x4 micro-tile, BK=16.
// z=0: hpE2[r][o]   = S * exp2(K*(hid.Wh)[r][o]) / v[o]       (row-major)
// z=1: epE[b][o][s] = exp2(K*((enc.We)[r][o] + bias[o]))      (TRANSPOSED)
// ---------------------------------------------------------------------------
__global__ __launch_bounds__(256) void proj_kernel(
    const float* __restrict__ hid, const float* __restrict__ enc,
    const float* __restrict__ W, const float* __restrict__ bias,
    const float* __restrict__ v,
    float* __restrict__ hpE2, float* __restrict__ epE)
{
    const int z = blockIdx.z;
    const float* __restrict__ X = z ? enc : hid;
    const int wofs = z ? TSD : 0;

    __shared__ float Xs[16][68];   // [k][m]
    __shared__ float Ws[16][68];   // [k][n]
    __shared__ float tile[64][68]; // transpose staging (z=1)

    const int tx = threadIdx.x, ty = threadIdx.y;
    const int tid = ty * 16 + tx;
    const int o0 = blockIdx.x * 64;
    const int r0 = blockIdx.y * 64;

    const int m  = tid >> 2;        // 0..63
    const int kq = (tid & 3) * 4;   // 0,4,8,12

    float acc[4][4] = {};

    for (int k0 = 0; k0 < TSD; k0 += 16) {
        __syncthreads();
        float4 av = *reinterpret_cast<const float4*>(&X[(r0 + m) * TSD + k0 + kq]);
        float4 wv = *reinterpret_cast<const float4*>(&W[(o0 + m) * (2 * TSD) + wofs + k0 + kq]);
        Xs[kq + 0][m] = av.x; Xs[kq + 1][m] = av.y; Xs[kq + 2][m] = av.z; Xs[kq + 3][m] = av.w;
        Ws[kq + 0][m] = wv.x; Ws[kq + 1][m] = wv.y; Ws[kq + 2][m] = wv.z; Ws[kq + 3][m] = wv.w;
        __syncthreads();
        #pragma unroll
        for (int k = 0; k < 16; ++k) {
            float4 a  = *reinterpret_cast<const float4*>(&Xs[k][ty * 4]);
            float4 bb = *reinterpret_cast<const float4*>(&Ws[k][tx * 4]);
            float ar[4] = {a.x, a.y, a.z, a.w};
            float br[4] = {bb.x, bb.y, bb.z, bb.w};
            #pragma unroll
            for (int i = 0; i < 4; ++i)
                #pragma unroll
                for (int j = 0; j < 4; ++j)
                    acc[i][j] = fmaf(ar[i], br[j], acc[i][j]);
        }
    }

    if (z) {
        const float b0 = bias[o0 + tx * 4 + 0];
        const float b1 = bias[o0 + tx * 4 + 1];
        const float b2 = bias[o0 + tx * 4 + 2];
        const float b3 = bias[o0 + tx * 4 + 3];
        __syncthreads();
        #pragma unroll
        for (int i = 0; i < 4; ++i) {
            float4 val;
            val.x = __builtin_amdgcn_exp2f((acc[i][0] + b0) * KSCALE);
            val.y = __builtin_amdgcn_exp2f((acc[i][1] + b1) * KSCALE);
            val.z = __builtin_amdgcn_exp2f((acc[i][2] + b2) * KSCALE);
            val.w = __builtin_amdgcn_exp2f((acc[i][3] + b3) * KSCALE);
            *reinterpret_cast<float4*>(&tile[ty * 4 + i][tx * 4]) = val;
        }
        __syncthreads();
        const int bb_ = r0 >> 8;
        const int s0  = (r0 & 255) + (tid & 15) * 4;
        #pragma unroll
        for (int it = 0; it < 4; ++it) {
            const int ol = it * 16 + (tid >> 4);
            float4 val;
            val.x = tile[(tid & 15) * 4 + 0][ol];
            val.y = tile[(tid & 15) * 4 + 1][ol];
            val.z = tile[(tid & 15) * 4 + 2][ol];
            val.w = tile[(tid & 15) * 4 + 3][ol];
            *reinterpret_cast<float4*>(&epE[((size_t)bb_ * TSD + o0 + ol) * SRC + s0]) = val;
        }
    } else {
        const int oc = o0 + tx * 4;
        float iv[4];
        #pragma unroll
        for (int j = 0; j < 4; ++j)
            iv[j] = SCALE * __builtin_amdgcn_rcpf(fmaxf(v[oc + j], EPSV));
        #pragma unroll
        for (int i = 0; i < 4; ++i) {
            const int r = r0 + ty * 4 + i;
            float4 o4;
            o4.x = __builtin_amdgcn_exp2f(acc[i][0] * KSCALE) * iv[0];
            o4.y = __builtin_amdgcn_exp2f(acc[i][1] * KSCALE) * iv[1];
            o4.z = __builtin_amdgcn_exp2f(acc[i][2] * KSCALE) * iv[2];
            o4.w = __builtin_amdgcn_exp2f(acc[i][3] * KSCALE) * iv[3];
            *reinterpret_cast<float4*>(&hpE2[r * TSD + oc]) = o4;
        }
    }
}

__device__ __forceinline__ float wave_red_sum(float v) {
    #pragma unroll
    for (int off = 1; off < 64; off <<= 1) v += __shfl_xor(v, off, 64);
    return v;
}
__device__ __forceinline__ float wave_red_max(float v) {
    #pragma unroll
    for (int off = 1; off < 64; off <<= 1) v = fmaxf(v, __shfl_xor(v, off, 64));
    return v;
}

// 4 t-rows at one s: w_t = eh_t*ee + iv (one fma each); 4 terms share one rcp
#define GRP4(EH, EE, IV, A0, A1, A2, A3) {                        \
    const float w0_ = fmaf((EH).x, (EE), IV);                     \
    const float w1_ = fmaf((EH).y, (EE), IV);                     \
    const float w2_ = fmaf((EH).z, (EE), IV);                     \
    const float w3_ = fmaf((EH).w, (EE), IV);                     \
    const float p01_ = w0_ * w1_;                                 \
    const float p23_ = w2_ * w3_;                                 \
    const float r_   = __builtin_amdgcn_rcpf(p01_ * p23_);        \
    const float rp01_ = r_ * p01_;                                \
    const float rp23_ = r_ * p23_;                                \
    A0 = fmaf(rp23_, w1_, A0); A1 = fmaf(rp23_, w0_, A1);         \
    A2 = fmaf(rp01_, w3_, A2); A3 = fmaf(rp01_, w2_, A3); }

// ---------------------------------------------------------------------------
// Phase A: P[t][s] = sum_o v[o]/(Eh*Ee+1)   (S and 1/v folded: w'=Eh2s*Ee+ivs)
// TB=8 target rows per block (halves epE re-read traffic vs TB=4).
// Grid (TGT/8, NB, 2 s-halves), 1024 thr = 16 waves; wave owns 32-o slice;
// lane owns 2 consecutive s (float2 ee loads); two 4-way rcp groups per (o,s).
// Output P -> probs region of d_out (Phase B finalizes in place).
// ---------------------------------------------------------------------------
__global__ __launch_bounds__(1024) void score_kernel(
    const float* __restrict__ hpE2, const float* __restrict__ epE,
    const float* __restrict__ v, float* __restrict__ P_out)
{
    __shared__ float4 ehA[TSD];          // Eh2s rows t0..t0+3   (8 KB)
    __shared__ float4 ehB[TSD];          // Eh2s rows t0+4..t0+7 (8 KB)
    __shared__ float ivs[TSD];           // S/v[o]               (2 KB)
    __shared__ float accs[8][16][128];   // [t][wave][s_local]   (64 KB)

    const int tid = threadIdx.x;
    const int b  = blockIdx.y;
    const int t0 = blockIdx.x * 8;
    const int sh = blockIdx.z;          // s-half

    // stage Eh2s for 8 rows (packed float4-by-t) + ivs
    {
        const int row = tid >> 7;            // 0..7
        const int oq  = (tid & 127) * 4;
        const float4 hh = *reinterpret_cast<const float4*>(
            &hpE2[((size_t)(b * TGT + t0 + row)) * TSD + oq]);
        float4* dst = (row < 4) ? ehA : ehB;
        const int rr = row & 3;
        ((float*)&dst[oq + 0])[rr] = hh.x;
        ((float*)&dst[oq + 1])[rr] = hh.y;
        ((float*)&dst[oq + 2])[rr] = hh.z;
        ((float*)&dst[oq + 3])[rr] = hh.w;
        if (tid < TSD) ivs[tid] = SCALE * __builtin_amdgcn_rcpf(fmaxf(v[tid], EPSV));
    }
    __syncthreads();

    const int w    = __builtin_amdgcn_readfirstlane(tid >> 6);  // wave 0..15
    const int lane = tid & 63;
    const int obase = w * 32;
    const float* __restrict__ epb =
        epE + (size_t)b * TSD * SRC + (size_t)obase * SRC + sh * 128 + 2 * lane;

    float aA[4][2] = {};   // rows t0..t0+3, [t][s-sub]
    float aB[4][2] = {};   // rows t0+4..t0+7
    #pragma unroll 4
    for (int oi = 0; oi < 32; ++oi) {
        const int o = obase + oi;
        const float2 ee = *reinterpret_cast<const float2*>(epb + (size_t)oi * SRC);
        const float4 eA = ehA[o];       // uniform -> ds_read_b128 broadcast
        const float4 eB = ehB[o];
        const float  iv = ivs[o];       // uniform -> ds_read_b32 broadcast
        GRP4(eA, ee.x, iv, aA[0][0], aA[1][0], aA[2][0], aA[3][0])
        GRP4(eA, ee.y, iv, aA[0][1], aA[1][1], aA[2][1], aA[3][1])
        GRP4(eB, ee.x, iv, aB[0][0], aB[1][0], aB[2][0], aB[3][0])
        GRP4(eB, ee.y, iv, aB[0][1], aB[1][1], aB[2][1], aB[3][1])
    }
    #pragma unroll
    for (int t = 0; t < 4; ++t) {
        float2 rA; rA.x = aA[t][0]; rA.y = aA[t][1];
        float2 rB; rB.x = aB[t][0]; rB.y = aB[t][1];
        *reinterpret_cast<float2*>(&accs[t][w][2 * lane])     = rA;
        *reinterpret_cast<float2*>(&accs[t + 4][w][2 * lane]) = rB;
    }
    __syncthreads();

    // combine 16 waves, write P (re-apply S): thread owns (t = tid>>7, s = tid&127)
    {
        const int t = tid >> 7;
        const int s = tid & 127;
        float Psum = 0.f;
        #pragma unroll
        for (int k = 0; k < 16; ++k) Psum += accs[t][k][s];
        P_out[((size_t)(b * TGT + t0 + t)) * SRC + sh * 128 + s] = Psum * SCALE;
    }
}

// ---------------------------------------------------------------------------
// Phase B: softmax. One wave per target row (4 rows/block). In-place on probs.
// ---------------------------------------------------------------------------
__global__ __launch_bounds__(256) void softmax_kernel(
    const int* __restrict__ mask, const float* __restrict__ v,
    float* __restrict__ probs)
{
    const int tid  = threadIdx.x;
    const int lane = tid & 63;
    const int rowg = blockIdx.x * 4 + (tid >> 6);   // global row: b*TGT + t
    const int b    = rowg >> 8;

    float sv = 0.f;
    #pragma unroll
    for (int k = 0; k < 8; ++k) sv += v[lane + 64 * k];
    const float sumv = wave_red_sum(sv);

    const size_t base = (size_t)rowg * SRC + 4 * lane;
    const float4 Pv = *reinterpret_cast<const float4*>(&probs[base]);
    float sc[4];
    sc[0] = sumv - 2.f * Pv.x;
    sc[1] = sumv - 2.f * Pv.y;
    sc[2] = sumv - 2.f * Pv.z;
    sc[3] = sumv - 2.f * Pv.w;

    const float lmax = fmaxf(fmaxf(sc[0], sc[1]), fmaxf(sc[2], sc[3]));
    const float m = wave_red_max(lmax);
    float e[4];
    #pragma unroll
    for (int i = 0; i < 4; ++i) e[i] = __expf(sc[i] - m);
    const float sE = wave_red_sum(e[0] + e[1] + e[2] + e[3]);

    const int4 mk = *reinterpret_cast<const int4*>(&mask[b * SRC + 4 * lane]);
    float mq[4];
    mq[0] = (e[0] / sE) * (float)mk.x;
    mq[1] = (e[1] / sE) * (float)mk.y;
    mq[2] = (e[2] / sE) * (float)mk.z;
    mq[3] = (e[3] / sE) * (float)mk.w;
    const float sM = wave_red_sum(mq[0] + mq[1] + mq[2] + mq[3]);
    const float inv = 1.f / (sM + 1e-12f);
    float4 pv;
    pv.x = mq[0] * inv; pv.y = mq[1] * inv; pv.z = mq[2] * inv; pv.w = mq[3] * inv;
    *reinterpret_cast<float4*>(&probs[base]) = pv;
}

// ---------------------------------------------------------------------------
// Phase C: context. Grid (TGT/4, NB, 2 d-halves), 256 thr.
// ---------------------------------------------------------------------------
__global__ __launch_bounds__(256) void ctx_kernel(
    const float* __restrict__ probs, const float* __restrict__ enc,
    float* __restrict__ ctx_out)
{
    __shared__ float p_lds[4][SRC];

    const int tid = threadIdx.x;
    const int b   = blockIdx.y;
    const int t0  = blockIdx.x * 4;
    const int dh  = blockIdx.z;

    #pragma unroll
    for (int t = 0; t < 4; ++t)
        p_lds[t][tid] = probs[((size_t)(b * TGT + t0 + t)) * SRC + tid];
    __syncthreads();

    const float* __restrict__ encb = enc + (size_t)b * SRC * TSD + dh * 256 + tid;
    float c0 = 0.f, c1 = 0.f, c2 = 0.f, c3 = 0.f;
    #pragma unroll 4
    for (int s2 = 0; s2 < SRC; ++s2) {
        const float ev = encb[(size_t)s2 * TSD];
        c0 = fmaf(p_lds[0][s2], ev, c0);
        c1 = fmaf(p_lds[1][s2], ev, c1);
        c2 = fmaf(p_lds[2][s2], ev, c2);
        c3 = fmaf(p_lds[3][s2], ev, c3);
    }
    const size_t obase = ((size_t)(b * TGT + t0)) * TSD + dh * 256 + tid;
    ctx_out[obase]           = c0;
    ctx_out[obase + TSD]     = c1;
    ctx_out[obase + 2 * TSD] = c2;
    ctx_out[obase + 3 * TSD] = c3;
}

extern "C" void kernel_launch(void* const* d_in, const int* in_sizes, int n_in,
                              void* d_out, int out_size, void* d_ws, size_t ws_size,
                              hipStream_t stream) {
    const float* hid  = (const float*)d_in[0];   // (4,256,512)
    const float* enc  = (const float*)d_in[1];   // (4,256,512)
    const int*   mask = (const int*)  d_in[2];   // (4,256)
    const float* W    = (const float*)d_in[3];   // (512,1024)
    const float* bias = (const float*)d_in[4];   // (512,)
    const float* v    = (const float*)d_in[5];   // (512,)

    float* out   = (float*)d_out;
    float* ctx   = out;                       // 4*256*512
    float* probs = out + NB * TGT * TSD;      // 4*256*256 (holds P, then probs)

    float* hpE2 = (float*)d_ws;               // 1024*512: S*exp2(K*h)/v    2 MB
    float* epE  = hpE2 + NB * TGT * TSD;      // 4*512*256: exp2(K*(e+b))^T 2 MB

    dim3 pb(16, 16);
    dim3 pg(TSD / 64, (NB * TGT) / 64, 2);
    proj_kernel<<<pg, pb, 0, stream>>>(hid, enc, W, bias, v, hpE2, epE);

    dim3 ag(TGT / 8, NB, 2);
    score_kernel<<<ag, 1024, 0, stream>>>(hpE2, epE, v, probs);

    softmax_kernel<<<dim3(NB * TGT / 4), 256, 0, stream>>>(mask, v, probs);

    dim3 cg(TGT / 4, NB, 2);
    ctx_kernel<<<cg, 256, 0, stream>>>(probs, enc, ctx);
}

// Round 14
// 66.264 us; speedup vs baseline: 1.4345x; 1.0728x over previous
//
#include <hip/hip_runtime.h>

#define TSD 512      // TS (feature dim)
#define SRC 256
#define TGT 256
#define NB  4        // batch
#define KSCALE 2.885390081777927f       // 2*log2(e): exp2(K*x) == exp(2x)
#define SCALE  9.5367431640625e-07f     // 2^-20: overflow headroom for 4-way product
#define EPSV   1e-20f

// ---------------------------------------------------------------------------
// Projection GEMM (R9-proven): 64x64 tiles, 4x4 micro-tile, BK=16.
// z=0: hpE2[r][o]   = S * exp2(K*(hid.Wh)[r][o]) / v[o]       (row-major)
// z=1: epE[b][o][s] = exp2(K*((enc.We)[r][o] + bias[o]))      (TRANSPOSED)
// ---------------------------------------------------------------------------
__global__ __launch_bounds__(256) void proj_kernel(
    const float* __restrict__ hid, const float* __restrict__ enc,
    const float* __restrict__ W, const float* __restrict__ bias,
    const float* __restrict__ v,
    float* __restrict__ hpE2, float* __restrict__ epE)
{
    const int z = blockIdx.z;
    const float* __restrict__ X = z ? enc : hid;
    const int wofs = z ? TSD : 0;

    __shared__ float Xs[16][68];   // [k][m]
    __shared__ float Ws[16][68];   // [k][n]
    __shared__ float tile[64][68]; // transpose staging (z=1)

    const int tx = threadIdx.x, ty = threadIdx.y;
    const int tid = ty * 16 + tx;
    const int o0 = blockIdx.x * 64;
    const int r0 = blockIdx.y * 64;

    const int m  = tid >> 2;        // 0..63
    const int kq = (tid & 3) * 4;   // 0,4,8,12

    float acc[4][4] = {};

    for (int k0 = 0; k0 < TSD; k0 += 16) {
        __syncthreads();
        float4 av = *reinterpret_cast<const float4*>(&X[(r0 + m) * TSD + k0 + kq]);
        float4 wv = *reinterpret_cast<const float4*>(&W[(o0 + m) * (2 * TSD) + wofs + k0 + kq]);
        Xs[kq + 0][m] = av.x; Xs[kq + 1][m] = av.y; Xs[kq + 2][m] = av.z; Xs[kq + 3][m] = av.w;
        Ws[kq + 0][m] = wv.x; Ws[kq + 1][m] = wv.y; Ws[kq + 2][m] = wv.z; Ws[kq + 3][m] = wv.w;
        __syncthreads();
        #pragma unroll
        for (int k = 0; k < 16; ++k) {
            float4 a  = *reinterpret_cast<const float4*>(&Xs[k][ty * 4]);
            float4 bb = *reinterpret_cast<const float4*>(&Ws[k][tx * 4]);
            float ar[4] = {a.x, a.y, a.z, a.w};
            float br[4] = {bb.x, bb.y, bb.z, bb.w};
            #pragma unroll
            for (int i = 0; i < 4; ++i)
                #pragma unroll
                for (int j = 0; j < 4; ++j)
                    acc[i][j] = fmaf(ar[i], br[j], acc[i][j]);
        }
    }

    if (z) {
        const float b0 = bias[o0 + tx * 4 + 0];
        const float b1 = bias[o0 + tx * 4 + 1];
        const float b2 = bias[o0 + tx * 4 + 2];
        const float b3 = bias[o0 + tx * 4 + 3];
        __syncthreads();
        #pragma unroll
        for (int i = 0; i < 4; ++i) {
            float4 val;
            val.x = __builtin_amdgcn_exp2f((acc[i][0] + b0) * KSCALE);
            val.y = __builtin_amdgcn_exp2f((acc[i][1] + b1) * KSCALE);
            val.z = __builtin_amdgcn_exp2f((acc[i][2] + b2) * KSCALE);
            val.w = __builtin_amdgcn_exp2f((acc[i][3] + b3) * KSCALE);
            *reinterpret_cast<float4*>(&tile[ty * 4 + i][tx * 4]) = val;
        }
        __syncthreads();
        const int bb_ = r0 >> 8;
        const int s0  = (r0 & 255) + (tid & 15) * 4;
        #pragma unroll
        for (int it = 0; it < 4; ++it) {
            const int ol = it * 16 + (tid >> 4);
            float4 val;
            val.x = tile[(tid & 15) * 4 + 0][ol];
            val.y = tile[(tid & 15) * 4 + 1][ol];
            val.z = tile[(tid & 15) * 4 + 2][ol];
            val.w = tile[(tid & 15) * 4 + 3][ol];
            *reinterpret_cast<float4*>(&epE[((size_t)bb_ * TSD + o0 + ol) * SRC + s0]) = val;
        }
    } else {
        const int oc = o0 + tx * 4;
        float iv[4];
        #pragma unroll
        for (int j = 0; j < 4; ++j)
            iv[j] = SCALE * __builtin_amdgcn_rcpf(fmaxf(v[oc + j], EPSV));
        #pragma unroll
        for (int i = 0; i < 4; ++i) {
            const int r = r0 + ty * 4 + i;
            float4 o4;
            o4.x = __builtin_amdgcn_exp2f(acc[i][0] * KSCALE) * iv[0];
            o4.y = __builtin_amdgcn_exp2f(acc[i][1] * KSCALE) * iv[1];
            o4.z = __builtin_amdgcn_exp2f(acc[i][2] * KSCALE) * iv[2];
            o4.w = __builtin_amdgcn_exp2f(acc[i][3] * KSCALE) * iv[3];
            *reinterpret_cast<float4*>(&hpE2[r * TSD + oc]) = o4;
        }
    }
}

__device__ __forceinline__ float wave_red_sum(float v) {
    #pragma unroll
    for (int off = 1; off < 64; off <<= 1) v += __shfl_xor(v, off, 64);
    return v;
}
__device__ __forceinline__ float wave_red_max(float v) {
    #pragma unroll
    for (int off = 1; off < 64; off <<= 1) v = fmaxf(v, __shfl_xor(v, off, 64));
    return v;
}

// 4 t-rows at one s: w_t = eh_t*ee + iv (one fma each); 4 terms share one rcp
#define GRP4(EH, EE, IV, A0, A1, A2, A3) {                        \
    const float w0_ = fmaf((EH).x, (EE), IV);                     \
    const float w1_ = fmaf((EH).y, (EE), IV);                     \
    const float w2_ = fmaf((EH).z, (EE), IV);                     \
    const float w3_ = fmaf((EH).w, (EE), IV);                     \
    const float p01_ = w0_ * w1_;                                 \
    const float p23_ = w2_ * w3_;                                 \
    const float r_   = __builtin_amdgcn_rcpf(p01_ * p23_);        \
    const float rp01_ = r_ * p01_;                                \
    const float rp23_ = r_ * p23_;                                \
    A0 = fmaf(rp23_, w1_, A0); A1 = fmaf(rp23_, w0_, A1);         \
    A2 = fmaf(rp01_, w3_, A2); A3 = fmaf(rp01_, w2_, A3); }

// ---------------------------------------------------------------------------
// Fused score + softmax + context. Grid (TGT/4, NB), 1024 thr = 16 waves.
// Wave w: s-half = w>>3, o-slice = (w&7)*64; lane owns 2 consecutive s.
// Score math identical to R9: w' = Eh2s*Ee + ivs, 4-way rcp share.
// Per-t LDS combine (8KB, reused x4) -> block softmax -> LDS-probs context.
// ---------------------------------------------------------------------------
__global__ __launch_bounds__(1024) void attn_fused_kernel(
    const float* __restrict__ hpE2, const float* __restrict__ epE,
    const float* __restrict__ v, const int* __restrict__ mask,
    const float* __restrict__ enc,
    float* __restrict__ ctx_out, float* __restrict__ probs_out)
{
    __shared__ float4 eh4[TSD];       // Eh2s packed by t       (8 KB)
    __shared__ float  ivs[TSD];       // S/v[o]                 (2 KB)
    __shared__ float  red8[8][SRC];   // o-slice partials       (8 KB, reused per t)
    __shared__ float  Plds[4][SRC];   // P, then probs          (4 KB)
    __shared__ float  redgA[4][4];
    __shared__ float  redgB[4][4];

    const int tid = threadIdx.x;
    const int b  = blockIdx.y;
    const int t0 = blockIdx.x * 4;

    // ---- stage Eh2s (4 rows packed per o) + ivs ----
    if (tid < 512) {
        const int row = tid >> 7;            // 0..3
        const int oq  = (tid & 127) * 4;
        const float4 hh = *reinterpret_cast<const float4*>(
            &hpE2[((size_t)(b * TGT + t0 + row)) * TSD + oq]);
        ((float*)&eh4[oq + 0])[row] = hh.x;
        ((float*)&eh4[oq + 1])[row] = hh.y;
        ((float*)&eh4[oq + 2])[row] = hh.z;
        ((float*)&eh4[oq + 3])[row] = hh.w;
    } else {
        const int o = tid - 512;
        ivs[o] = SCALE * __builtin_amdgcn_rcpf(fmaxf(v[o], EPSV));
    }
    __syncthreads();

    // ---- score partials (R9-proven inner loop) ----
    const int w    = __builtin_amdgcn_readfirstlane(tid >> 6);  // wave 0..15
    const int lane = tid & 63;
    const int sh   = w >> 3;                                    // s-half
    const int ow   = w & 7;                                     // o-slice
    const int obase = ow * 64;
    const float* __restrict__ epb =
        epE + (size_t)b * TSD * SRC + (size_t)obase * SRC + sh * 128 + 2 * lane;

    float acc[4][2] = {};   // [t][s-sub]
    #pragma unroll 4
    for (int oi = 0; oi < 64; ++oi) {
        const int o = obase + oi;
        const float2 ee = *reinterpret_cast<const float2*>(epb + (size_t)oi * SRC);
        const float4 eh = eh4[o];       // uniform -> ds_read_b128 broadcast
        const float  iv = ivs[o];       // uniform -> ds_read_b32 broadcast
        GRP4(eh, ee.x, iv, acc[0][0], acc[1][0], acc[2][0], acc[3][0])
        GRP4(eh, ee.y, iv, acc[0][1], acc[1][1], acc[2][1], acc[3][1])
    }

    // ---- combine 8 o-slices per t (red8 reused across t) ----
    #pragma unroll
    for (int t = 0; t < 4; ++t) {
        __syncthreads();                 // red8 free (prev t consumed / first use)
        float2 r2; r2.x = acc[t][0]; r2.y = acc[t][1];
        *reinterpret_cast<float2*>(&red8[ow][sh * 128 + 2 * lane]) = r2;
        __syncthreads();
        if (tid < SRC) {
            float Ps = 0.f;
            #pragma unroll
            for (int r = 0; r < 8; ++r) Ps += red8[r][tid];
            Plds[t][tid] = Ps * SCALE;
        }
    }
    __syncthreads();

    // ---- softmax: group g = tid>>8 handles row t0+g, s = tid&255 ----
    const int g = __builtin_amdgcn_readfirstlane(tid >> 8);
    const int s = tid & 255;
    const int wig = (tid >> 6) & 3;      // wave index within group

    float sv = v[s] + v[s + 256];
    {
        float wsv = wave_red_sum(sv);
        if ((tid & 63) == 0) redgA[g][wig] = wsv;
    }
    __syncthreads();
    const float sumv = redgA[g][0] + redgA[g][1] + redgA[g][2] + redgA[g][3];
    const float score = sumv - 2.f * Plds[g][s];

    {
        float wm = wave_red_max(score);
        if ((tid & 63) == 0) redgB[g][wig] = wm;
    }
    __syncthreads();
    const float mx = fmaxf(fmaxf(redgB[g][0], redgB[g][1]), fmaxf(redgB[g][2], redgB[g][3]));
    const float e = __expf(score - mx);
    {
        float ws = wave_red_sum(e);
        if ((tid & 63) == 0) redgA[g][wig] = ws;
    }
    __syncthreads();
    const float sE = redgA[g][0] + redgA[g][1] + redgA[g][2] + redgA[g][3];
    const float mq = (e / sE) * (float)mask[b * SRC + s];
    {
        float ws = wave_red_sum(mq);
        if ((tid & 63) == 0) redgB[g][wig] = ws;
    }
    __syncthreads();
    const float sM = redgB[g][0] + redgB[g][1] + redgB[g][2] + redgB[g][3];
    const float p = mq / (sM + 1e-12f);
    __syncthreads();                      // Plds[g][s] reads done before overwrite
    Plds[g][s] = p;
    probs_out[((size_t)(b * TGT + t0 + g)) * SRC + s] = p;
    __syncthreads();

    // ---- context: group pair dg = tid>>9 handles rows {2dg, 2dg+1}; d = tid&511 ----
    const int dg = tid >> 9;
    const int d  = tid & 511;
    const float* __restrict__ encb = enc + (size_t)b * SRC * TSD + d;
    float c0 = 0.f, c1 = 0.f;
    #pragma unroll 4
    for (int s2 = 0; s2 < SRC; ++s2) {
        const float ev = encb[(size_t)s2 * TSD];
        c0 = fmaf(Plds[2 * dg + 0][s2], ev, c0);
        c1 = fmaf(Plds[2 * dg + 1][s2], ev, c1);
    }
    ctx_out[((size_t)(b * TGT + t0 + 2 * dg + 0)) * TSD + d] = c0;
    ctx_out[((size_t)(b * TGT + t0 + 2 * dg + 1)) * TSD + d] = c1;
}

extern "C" void kernel_launch(void* const* d_in, const int* in_sizes, int n_in,
                              void* d_out, int out_size, void* d_ws, size_t ws_size,
                              hipStream_t stream) {
    const float* hid  = (const float*)d_in[0];   // (4,256,512)
    const float* enc  = (const float*)d_in[1];   // (4,256,512)
    const int*   mask = (const int*)  d_in[2];   // (4,256)
    const float* W    = (const float*)d_in[3];   // (512,1024)
    const float* bias = (const float*)d_in[4];   // (512,)
    const float* v    = (const float*)d_in[5];   // (512,)

    float* out   = (float*)d_out;
    float* ctx   = out;                       // 4*256*512
    float* probs = out + NB * TGT * TSD;      // 4*256*256

    float* hpE2 = (float*)d_ws;               // 1024*512: S*exp2(K*h)/v    2 MB
    float* epE  = hpE2 + NB * TGT * TSD;      // 4*512*256: exp2(K*(e+b))^T 2 MB

    dim3 pb(16, 16);
    dim3 pg(TSD / 64, (NB * TGT) / 64, 2);
    proj_kernel<<<pg, pb, 0, stream>>>(hid, enc, W, bias, v, hpE2, epE);

    dim3 ag(TGT / 4, NB);
    attn_fused_kernel<<<ag, 1024, 0, stream>>>(hpE2, epE, v, mask, enc, ctx, probs);
}